// Round 12
// baseline (154.554 us; speedup 1.0000x reference)
//
#include <hip/hip_runtime.h>
#include <hip/hip_bf16.h>

// out[t,l] = sum_{ijk} p1[t,i] p2[t,j] p3[t,k] grid[i,j,k,l]
// GEMM M=16384, K=4096 (k=i*256+j*16+kk), N=768; A built in registers.
// v11: NO LDS staging for B. grid is pre-packed (k_pack) into fragment-order
//      gT2 (f16): fragment (nb,kt,s) = 1024 contiguous bytes, lane-major,
//      matching the v5-verified mfma_32x32x16 B layout. k_gemm reads B
//      directly from L2/L3 (6.3 MB resident) with coalesced dwordx4 —
//      zero barriers in the K-loop, no LDS pipe contention.

using f32x2  = __attribute__((ext_vector_type(2))) float;
using f32x4  = __attribute__((ext_vector_type(4))) float;
using f32x16 = __attribute__((ext_vector_type(16))) float;
using half8  = __attribute__((ext_vector_type(8))) _Float16;
using half2v = __attribute__((ext_vector_type(2))) _Float16;
typedef unsigned short ushort_t;
typedef unsigned int uint_t;

#define PSTRIDE 52            // p row stride (floats)

static __device__ __forceinline__ ushort_t f2h_bits(float x) {
  union { _Float16 h; ushort_t u; } c;
  c.h = (_Float16)x;          // RNE
  return c.u;
}

static __device__ __forceinline__ half2v cvt_pkrtz2(float a, float b) {
  auto r = __builtin_amdgcn_cvt_pkrtz(a, b);
  union { decltype(r) i; half2v o; } u;
  u.i = r;
  return u.o;
}

// ---------------------------------------------------------------------------
// Kernel 1: grid (4096 x 768 f32) -> gT2 fragment-ordered f16.
// gT2 ushort index: ((nb*64 + kt)*4 + s)*512 + lane*8 + e
// value = grid[kt*64 + s*16 + 8*(lane>>5) + e][nb*32 + (lane&31)]
// ---------------------------------------------------------------------------
__global__ __launch_bounds__(256) void k_pack(const float* __restrict__ g,
                                              ushort_t* __restrict__ gT2) {
  const int t = threadIdx.x;
  const int kt = blockIdx.x;                  // 0..63
  const int nb = blockIdx.y;                  // 0..23
  const int s = t >> 6, l = t & 63;
  const int krow = kt * 64 + s * 16 + 8 * (l >> 5);
  const int n = nb * 32 + (l & 31);
  const float* src = g + (size_t)krow * 768 + n;
  union { ushort_t us[8]; uint4 v; } o;
#pragma unroll
  for (int e = 0; e < 8; ++e) o.us[e] = f2h_bits(src[(size_t)e * 768]);
  *(uint4*)(gT2 + ((size_t)((nb * 64 + kt) * 4 + s) * 64 + l) * 8) = o.v;
}

// ---------------------------------------------------------------------------
// Kernel 2: p[t][48] = softmax16((x@W + b)/temp)  (unchanged)
// ---------------------------------------------------------------------------
__global__ __launch_bounds__(512) void k_prep(const float* __restrict__ x,
                                              const float* __restrict__ W1, const float* __restrict__ b1,
                                              const float* __restrict__ W2, const float* __restrict__ b2,
                                              const float* __restrict__ W3, const float* __restrict__ b3,
                                              const float* __restrict__ temp,
                                              float* __restrict__ p) {
  __shared__ union SmT {
    float x2[2][64][100];                   // 51,200 B
    float partial[4][64][PSTRIDE];          // 53,248 B
  } sm;
  const int tid = threadIdx.x;
  const int lane = tid & 63;
  const int wv = __builtin_amdgcn_readfirstlane(tid >> 6);  // 0..7 = d-slice
  const int t0 = blockIdx.x * 64;

  float acc[48];
#pragma unroll
  for (int q = 0; q < 48; ++q) acc[q] = 0.f;
  f32x2* a2 = (f32x2*)acc;

  const float* xbase = x + (size_t)t0 * 768;
  auto load_chunk = [&](int c, int b) {
#pragma unroll
    for (int it = 0; it < 3; ++it) {
      const int q = tid + it * 512;         // 0..1535
      const int r = q / 24;
      const int c4 = q % 24;
      const float4 v = *(const float4*)(xbase + (size_t)r * 768 + c * 96 + c4 * 4);
      *(float4*)&sm.x2[b][r][c4 * 4] = v;
    }
  };

  load_chunk(0, 0);
  __syncthreads();
  for (int c = 0; c < 8; ++c) {
    const int cur = c & 1;
    if (c < 7) load_chunk(c + 1, cur ^ 1);
    float xv[12];
#pragma unroll
    for (int rr = 0; rr < 3; ++rr) {
      const f32x4 v = *(const f32x4*)&sm.x2[cur][lane][wv * 12 + rr * 4];
      xv[rr * 4 + 0] = v[0]; xv[rr * 4 + 1] = v[1];
      xv[rr * 4 + 2] = v[2]; xv[rr * 4 + 3] = v[3];
    }
#pragma unroll
    for (int dd = 0; dd < 12; ++dd) {
      const int d = c * 96 + wv * 12 + dd;
      const float xs = xv[dd];
      const f32x2 xs2 = {xs, xs};
      const f32x2* w1r = (const f32x2*)(W1 + d * 16);
      const f32x2* w2r = (const f32x2*)(W2 + d * 16);
      const f32x2* w3r = (const f32x2*)(W3 + d * 16);
#pragma unroll
      for (int gg = 0; gg < 8; ++gg) {
        a2[gg]      = __builtin_elementwise_fma(xs2, w1r[gg], a2[gg]);
        a2[8 + gg]  = __builtin_elementwise_fma(xs2, w2r[gg], a2[8 + gg]);
        a2[16 + gg] = __builtin_elementwise_fma(xs2, w3r[gg], a2[16 + gg]);
      }
    }
    __syncthreads();
  }

  // tree reduce 8 -> 4 -> 2 -> 1
  if (wv >= 4) {
    f32x4* dst = (f32x4*)sm.partial[wv - 4][lane];
#pragma unroll
    for (int q = 0; q < 12; ++q) dst[q] = *(const f32x4*)&acc[q * 4];
  }
  __syncthreads();
  if (wv < 4) {
    const f32x4* src = (const f32x4*)sm.partial[wv][lane];
#pragma unroll
    for (int q = 0; q < 12; ++q) {
      const f32x4 v = src[q];
#pragma unroll
      for (int e = 0; e < 4; ++e) acc[q * 4 + e] += v[e];
    }
  }
  __syncthreads();
  if (wv == 2 || wv == 3) {
    f32x4* dst = (f32x4*)sm.partial[wv - 2][lane];
#pragma unroll
    for (int q = 0; q < 12; ++q) dst[q] = *(const f32x4*)&acc[q * 4];
  }
  __syncthreads();
  if (wv < 2) {
    const f32x4* src = (const f32x4*)sm.partial[wv][lane];
#pragma unroll
    for (int q = 0; q < 12; ++q) {
      const f32x4 v = src[q];
#pragma unroll
      for (int e = 0; e < 4; ++e) acc[q * 4 + e] += v[e];
    }
  }
  __syncthreads();
  if (wv == 1) {
    f32x4* dst = (f32x4*)sm.partial[0][lane];
#pragma unroll
    for (int q = 0; q < 12; ++q) dst[q] = *(const f32x4*)&acc[q * 4];
  }
  __syncthreads();
  if (wv == 0) {
    const f32x4* src = (const f32x4*)sm.partial[0][lane];
#pragma unroll
    for (int q = 0; q < 12; ++q) {
      const f32x4 v = src[q];
#pragma unroll
      for (int e = 0; e < 4; ++e) acc[q * 4 + e] += v[e];
    }
    const float invT = 1.0f / temp[0];
    float* prow = p + (size_t)(t0 + lane) * PSTRIDE;
#pragma unroll
    for (int grp = 0; grp < 3; ++grp) {
      const float* bias = (grp == 0) ? b1 : (grp == 1) ? b2 : b3;
      float z[16];
      float m = -3.0e38f;
#pragma unroll
      for (int q = 0; q < 16; ++q) {
        z[q] = (acc[grp * 16 + q] + bias[q]) * invT;
        m = fmaxf(m, z[q]);
      }
      float s = 0.f;
#pragma unroll
      for (int q = 0; q < 16; ++q) { z[q] = __expf(z[q] - m); s += z[q]; }
      const float rs = 1.0f / s;
#pragma unroll
      for (int q = 0; q < 16; ++q) prow[grp * 16 + q] = z[q] * rs;
    }
  }
}

// ---------------------------------------------------------------------------
// Kernel 3: GEMM, barrier-free K-loop. BM=128 BN=192, 4 waves 2x2, wave
// tile 64x96 (mr=2, nf=3), v_mfma_f32_32x32x16_f16. B read directly from
// fragment-ordered gT2 via coalesced dwordx4 (no Bt LDS, no staging).
// Compiler inserts per-register counted vmcnt waits; waves drift freely.
// ---------------------------------------------------------------------------
__global__ __launch_bounds__(256, 2) void k_gemm(const float* __restrict__ p_g,
                                                 const ushort_t* __restrict__ gT2,
                                                 float* __restrict__ out) {
  __shared__ ushort_t p1h[16 * 128];          // 4,096 B

  const int tid = threadIdx.x;
  const int lane = tid & 63;
  const int wv = __builtin_amdgcn_readfirstlane(tid >> 6);
  const int wm = wv >> 1, wn = wv & 1;
  const int g = lane >> 5;                    // k-half 0/1
  const int l31 = lane & 31;

  // XCD swizzle over 512 blocks (512 % 8 == 0 -> bijective)
  const int f = blockIdx.y * 128 + blockIdx.x;
  const int w = (f & 7) * 64 + (f >> 3);
  const int m0 = (w & 127) * 128;             // token base
  const int n0 = (w >> 7) * 192;              // latent base

  // p1h[i*128+row] build (f16)
  if (tid < 128) {
    const float* pr = p_g + (size_t)(m0 + tid) * PSTRIDE;
#pragma unroll
    for (int qq = 0; qq < 4; ++qq) {
      const f32x4 v = *(const f32x4*)(pr + qq * 4);
#pragma unroll
      for (int e = 0; e < 4; ++e) p1h[(qq * 4 + e) * 128 + tid] = f2h_bits(v[e]);
    }
  }

  // per-lane p2 (16 broadcast pairs) / p3 (own k-half) for 2 m-rep rows
  half2v p2h[2][16];
  float p3r[2][8];
#pragma unroll
  for (int mr = 0; mr < 2; ++mr) {
    const float* pr = p_g + (size_t)(m0 + wm * 64 + mr * 32 + l31) * PSTRIDE;
#pragma unroll
    for (int qq = 0; qq < 4; ++qq) {
      const f32x4 v = *(const f32x4*)(pr + 16 + qq * 4);
#pragma unroll
      for (int e = 0; e < 4; ++e)
        p2h[mr][qq * 4 + e] = cvt_pkrtz2(v[e], v[e]);
    }
#pragma unroll
    for (int qq = 0; qq < 2; ++qq) {
      const f32x4 v = *(const f32x4*)(pr + 32 + 8 * g + qq * 4);
      p3r[mr][qq * 4 + 0] = v[0]; p3r[mr][qq * 4 + 1] = v[1];
      p3r[mr][qq * 4 + 2] = v[2]; p3r[mr][qq * 4 + 3] = v[3];
    }
  }

  // B fragment bases: nb(nf) = n0/32 + wn*3 + nf; frag (nb,kt,s) at
  // ushort offset ((nb*64+kt)*4+s)*512 + lane*8
  const ushort_t* bbase[3];
#pragma unroll
  for (int nf = 0; nf < 3; ++nf)
    bbase[nf] = gT2 + ((size_t)(n0 / 32 + wn * 3 + nf) * 64 * 4) * 512 + lane * 8;

  f32x16 acc[2][3];
#pragma unroll
  for (int mr = 0; mr < 2; ++mr)
#pragma unroll
    for (int nf = 0; nf < 3; ++nf)
#pragma unroll
      for (int e = 0; e < 16; ++e) acc[mr][nf][e] = 0.f;

  __syncthreads();                            // publish p1h (only barrier)

  for (int io = 0; io < 16; ++io) {           // i-index (p1)
    half2v p1p3h[2][4];
#pragma unroll
    for (int mr = 0; mr < 2; ++mr) {
      union { ushort_t u; _Float16 h; } c;
      c.u = p1h[io * 128 + wm * 64 + mr * 32 + l31];
      const float p1v = (float)c.h;
#pragma unroll
      for (int q = 0; q < 4; ++q)
        p1p3h[mr][q] = cvt_pkrtz2(p1v * p3r[mr][2 * q],
                                  p1v * p3r[mr][2 * q + 1]);
    }
#pragma unroll
    for (int kq = 0; kq < 4; ++kq) {
      const int kt = io * 4 + kq;

      // issue all 12 coalesced B-fragment loads (compiler: counted vmcnt)
      half8 b[4][3];
#pragma unroll
      for (int s = 0; s < 4; ++s)
#pragma unroll
        for (int nf = 0; nf < 3; ++nf)
          b[s][nf] = *(const half8*)&bbase[nf][(size_t)(kt * 4 + s) * 512];

#pragma unroll
      for (int s = 0; s < 4; ++s) {
        const int j = kq * 4 + s;             // static p2 index
        half8 a[2];
#pragma unroll
        for (int mr = 0; mr < 2; ++mr) {
          union { half2v h2[4]; half8 h8; } pk;
#pragma unroll
          for (int q = 0; q < 4; ++q) pk.h2[q] = p2h[mr][j] * p1p3h[mr][q];
          a[mr] = pk.h8;
        }
        __builtin_amdgcn_s_setprio(1);
#pragma unroll
        for (int mr = 0; mr < 2; ++mr)
#pragma unroll
          for (int nf = 0; nf < 3; ++nf)
            acc[mr][nf] = __builtin_amdgcn_mfma_f32_32x32x16_f16(a[mr], b[s][nf], acc[mr][nf], 0, 0, 0);
        __builtin_amdgcn_s_setprio(0);
      }
    }
  }

  // epilogue: 32x32 C/D: col = lane&31, row = (reg&3)+8*(reg>>2)+4*(lane>>5)
#pragma unroll
  for (int mr = 0; mr < 2; ++mr)
#pragma unroll
    for (int nf = 0; nf < 3; ++nf)
#pragma unroll
      for (int reg = 0; reg < 16; ++reg) {
        const int row = (reg & 3) + 8 * (reg >> 2) + 4 * g;
        const int t = m0 + wm * 64 + mr * 32 + row;
        out[(size_t)t * 768 + n0 + wn * 96 + nf * 32 + l31] = acc[mr][nf][reg];
      }
}

// ---------------------------------------------------------------------------
extern "C" void kernel_launch(void* const* d_in, const int* in_sizes, int n_in,
                              void* d_out, int out_size, void* d_ws, size_t ws_size,
                              hipStream_t stream) {
  (void)in_sizes; (void)n_in; (void)out_size; (void)ws_size;
  const float* x    = (const float*)d_in[0];
  const float* W1   = (const float*)d_in[1];
  const float* b1   = (const float*)d_in[2];
  const float* W2   = (const float*)d_in[3];
  const float* b2   = (const float*)d_in[4];
  const float* W3   = (const float*)d_in[5];
  const float* b3   = (const float*)d_in[6];
  const float* grid = (const float*)d_in[7];
  const float* temp = (const float*)d_in[8];
  float* out = (float*)d_out;

  // ws: gT2 f16 fragment-ordered = 6,291,456 B ; p f32 [16384][52] = 3,407,872 B
  ushort_t* gT2 = (ushort_t*)d_ws;
  float* p = (float*)((char*)d_ws + 6291456);

  k_pack<<<dim3(64, 24), 256, 0, stream>>>(grid, gT2);
  k_prep<<<dim3(256), 512, 0, stream>>>(x, W1, b1, W2, b2, W3, b3, temp, p);
  k_gemm<<<dim3(128, 4), 256, 0, stream>>>(p, gT2, out);
}

// Round 13
// 141.650 us; speedup vs baseline: 1.0911x; 1.0911x over previous
//
#include <hip/hip_runtime.h>
#include <hip/hip_bf16.h>

// out[t,l] = sum_{ijk} p1[t,i] p2[t,j] p3[t,k] grid[i,j,k,l]
// GEMM M=16384, K=4096 (k=i*256+j*16+kk), N=768; A built in registers.
// v12: fat wave + direct-L2 B + register double-buffer. BM=256 BN=192,
//      grid 256 = 1 block/CU, 4 waves 2x2, wave tile 128x96 (mr=4,nf=3,
//      48 MFMA/kt). B-demand/MFMA halved vs v11 -> VMEM return path at 50%.
//      Barrier-free K-loop; b regs double-buffered with static parity.

using f32x2  = __attribute__((ext_vector_type(2))) float;
using f32x4  = __attribute__((ext_vector_type(4))) float;
using f32x16 = __attribute__((ext_vector_type(16))) float;
using half8  = __attribute__((ext_vector_type(8))) _Float16;
using half2v = __attribute__((ext_vector_type(2))) _Float16;
typedef unsigned short ushort_t;
typedef unsigned int uint_t;

#define PSTRIDE 52            // p row stride (floats)

static __device__ __forceinline__ ushort_t f2h_bits(float x) {
  union { _Float16 h; ushort_t u; } c;
  c.h = (_Float16)x;          // RNE
  return c.u;
}

static __device__ __forceinline__ half2v cvt_pkrtz2(float a, float b) {
  auto r = __builtin_amdgcn_cvt_pkrtz(a, b);
  union { decltype(r) i; half2v o; } u;
  u.i = r;
  return u.o;
}

// ---------------------------------------------------------------------------
// Kernel 1: grid (4096 x 768 f32) -> gT2 fragment-ordered f16.
// gT2 ushort index: ((nb*64 + kt)*4 + s)*512 + lane*8 + e
// value = grid[kt*64 + s*16 + 8*(lane>>5) + e][nb*32 + (lane&31)]
// ---------------------------------------------------------------------------
__global__ __launch_bounds__(256) void k_pack(const float* __restrict__ g,
                                              ushort_t* __restrict__ gT2) {
  const int t = threadIdx.x;
  const int kt = blockIdx.x;                  // 0..63
  const int nb = blockIdx.y;                  // 0..23
  const int s = t >> 6, l = t & 63;
  const int krow = kt * 64 + s * 16 + 8 * (l >> 5);
  const int n = nb * 32 + (l & 31);
  const float* src = g + (size_t)krow * 768 + n;
  union { ushort_t us[8]; uint4 v; } o;
#pragma unroll
  for (int e = 0; e < 8; ++e) o.us[e] = f2h_bits(src[(size_t)e * 768]);
  *(uint4*)(gT2 + ((size_t)((nb * 64 + kt) * 4 + s) * 64 + l) * 8) = o.v;
}

// ---------------------------------------------------------------------------
// Kernel 2: p[t][48] = softmax16((x@W + b)/temp)  (unchanged)
// ---------------------------------------------------------------------------
__global__ __launch_bounds__(512) void k_prep(const float* __restrict__ x,
                                              const float* __restrict__ W1, const float* __restrict__ b1,
                                              const float* __restrict__ W2, const float* __restrict__ b2,
                                              const float* __restrict__ W3, const float* __restrict__ b3,
                                              const float* __restrict__ temp,
                                              float* __restrict__ p) {
  __shared__ union SmT {
    float x2[2][64][100];                   // 51,200 B
    float partial[4][64][PSTRIDE];          // 53,248 B
  } sm;
  const int tid = threadIdx.x;
  const int lane = tid & 63;
  const int wv = __builtin_amdgcn_readfirstlane(tid >> 6);  // 0..7 = d-slice
  const int t0 = blockIdx.x * 64;

  float acc[48];
#pragma unroll
  for (int q = 0; q < 48; ++q) acc[q] = 0.f;
  f32x2* a2 = (f32x2*)acc;

  const float* xbase = x + (size_t)t0 * 768;
  auto load_chunk = [&](int c, int b) {
#pragma unroll
    for (int it = 0; it < 3; ++it) {
      const int q = tid + it * 512;         // 0..1535
      const int r = q / 24;
      const int c4 = q % 24;
      const float4 v = *(const float4*)(xbase + (size_t)r * 768 + c * 96 + c4 * 4);
      *(float4*)&sm.x2[b][r][c4 * 4] = v;
    }
  };

  load_chunk(0, 0);
  __syncthreads();
  for (int c = 0; c < 8; ++c) {
    const int cur = c & 1;
    if (c < 7) load_chunk(c + 1, cur ^ 1);
    float xv[12];
#pragma unroll
    for (int rr = 0; rr < 3; ++rr) {
      const f32x4 v = *(const f32x4*)&sm.x2[cur][lane][wv * 12 + rr * 4];
      xv[rr * 4 + 0] = v[0]; xv[rr * 4 + 1] = v[1];
      xv[rr * 4 + 2] = v[2]; xv[rr * 4 + 3] = v[3];
    }
#pragma unroll
    for (int dd = 0; dd < 12; ++dd) {
      const int d = c * 96 + wv * 12 + dd;
      const float xs = xv[dd];
      const f32x2 xs2 = {xs, xs};
      const f32x2* w1r = (const f32x2*)(W1 + d * 16);
      const f32x2* w2r = (const f32x2*)(W2 + d * 16);
      const f32x2* w3r = (const f32x2*)(W3 + d * 16);
#pragma unroll
      for (int gg = 0; gg < 8; ++gg) {
        a2[gg]      = __builtin_elementwise_fma(xs2, w1r[gg], a2[gg]);
        a2[8 + gg]  = __builtin_elementwise_fma(xs2, w2r[gg], a2[8 + gg]);
        a2[16 + gg] = __builtin_elementwise_fma(xs2, w3r[gg], a2[16 + gg]);
      }
    }
    __syncthreads();
  }

  // tree reduce 8 -> 4 -> 2 -> 1
  if (wv >= 4) {
    f32x4* dst = (f32x4*)sm.partial[wv - 4][lane];
#pragma unroll
    for (int q = 0; q < 12; ++q) dst[q] = *(const f32x4*)&acc[q * 4];
  }
  __syncthreads();
  if (wv < 4) {
    const f32x4* src = (const f32x4*)sm.partial[wv][lane];
#pragma unroll
    for (int q = 0; q < 12; ++q) {
      const f32x4 v = src[q];
#pragma unroll
      for (int e = 0; e < 4; ++e) acc[q * 4 + e] += v[e];
    }
  }
  __syncthreads();
  if (wv == 2 || wv == 3) {
    f32x4* dst = (f32x4*)sm.partial[wv - 2][lane];
#pragma unroll
    for (int q = 0; q < 12; ++q) dst[q] = *(const f32x4*)&acc[q * 4];
  }
  __syncthreads();
  if (wv < 2) {
    const f32x4* src = (const f32x4*)sm.partial[wv][lane];
#pragma unroll
    for (int q = 0; q < 12; ++q) {
      const f32x4 v = src[q];
#pragma unroll
      for (int e = 0; e < 4; ++e) acc[q * 4 + e] += v[e];
    }
  }
  __syncthreads();
  if (wv == 1) {
    f32x4* dst = (f32x4*)sm.partial[0][lane];
#pragma unroll
    for (int q = 0; q < 12; ++q) dst[q] = *(const f32x4*)&acc[q * 4];
  }
  __syncthreads();
  if (wv == 0) {
    const f32x4* src = (const f32x4*)sm.partial[0][lane];
#pragma unroll
    for (int q = 0; q < 12; ++q) {
      const f32x4 v = src[q];
#pragma unroll
      for (int e = 0; e < 4; ++e) acc[q * 4 + e] += v[e];
    }
    const float invT = 1.0f / temp[0];
    float* prow = p + (size_t)(t0 + lane) * PSTRIDE;
#pragma unroll
    for (int grp = 0; grp < 3; ++grp) {
      const float* bias = (grp == 0) ? b1 : (grp == 1) ? b2 : b3;
      float z[16];
      float m = -3.0e38f;
#pragma unroll
      for (int q = 0; q < 16; ++q) {
        z[q] = (acc[grp * 16 + q] + bias[q]) * invT;
        m = fmaxf(m, z[q]);
      }
      float s = 0.f;
#pragma unroll
      for (int q = 0; q < 16; ++q) { z[q] = __expf(z[q] - m); s += z[q]; }
      const float rs = 1.0f / s;
#pragma unroll
      for (int q = 0; q < 16; ++q) prow[grp * 16 + q] = z[q] * rs;
    }
  }
}

// ---------------------------------------------------------------------------
// Kernel 3: GEMM. BM=256 BN=192; 4 waves 2x2, wave tile 128x96 (mr=4,nf=3).
// B direct from fragment-ordered gT2 (L2-resident), register double-buffer
// (bA/bB, static parity kt%2==kq%2). Barrier-free K-loop; loads for kt+1
// issued at body top, consumed 1550 cyc later. 1 block/CU, 1 wave/SIMD.
// ---------------------------------------------------------------------------
__global__ __launch_bounds__(256, 1) void k_gemm(const float* __restrict__ p_g,
                                                 const ushort_t* __restrict__ gT2,
                                                 float* __restrict__ out) {
  __shared__ ushort_t p1h[16 * 256];          // 8,192 B

  const int tid = threadIdx.x;
  const int lane = tid & 63;
  const int wv = __builtin_amdgcn_readfirstlane(tid >> 6);
  const int wm = wv >> 1, wn = wv & 1;
  const int g = lane >> 5;                    // k-half 0/1
  const int l31 = lane & 31;

  // XCD swizzle over 256 blocks (256 % 8 == 0 -> bijective)
  const int f = blockIdx.y * 64 + blockIdx.x;
  const int w = (f & 7) * 32 + (f >> 3);
  const int m0 = (w & 63) * 256;              // token base
  const int n0 = (w >> 6) * 192;              // latent base

  // p1h[i*256+row] build (each thread one row)
  {
    const float* pr = p_g + (size_t)(m0 + tid) * PSTRIDE;
#pragma unroll
    for (int qq = 0; qq < 4; ++qq) {
      const f32x4 v = *(const f32x4*)(pr + qq * 4);
#pragma unroll
      for (int e = 0; e < 4; ++e) p1h[(qq * 4 + e) * 256 + tid] = f2h_bits(v[e]);
    }
  }

  // per-lane p2 (16 broadcast pairs) / p3 (own k-half) for 4 m-rep rows
  half2v p2h[4][16];
  float p3r[4][8];
#pragma unroll
  for (int mr = 0; mr < 4; ++mr) {
    const float* pr = p_g + (size_t)(m0 + wm * 128 + mr * 32 + l31) * PSTRIDE;
#pragma unroll
    for (int qq = 0; qq < 4; ++qq) {
      const f32x4 v = *(const f32x4*)(pr + 16 + qq * 4);
#pragma unroll
      for (int e = 0; e < 4; ++e)
        p2h[mr][qq * 4 + e] = cvt_pkrtz2(v[e], v[e]);
    }
#pragma unroll
    for (int qq = 0; qq < 2; ++qq) {
      const f32x4 v = *(const f32x4*)(pr + 32 + 8 * g + qq * 4);
      p3r[mr][qq * 4 + 0] = v[0]; p3r[mr][qq * 4 + 1] = v[1];
      p3r[mr][qq * 4 + 2] = v[2]; p3r[mr][qq * 4 + 3] = v[3];
    }
  }

  // B fragment bases: nb(nf) = n0/32 + wn*3 + nf
  // frag (nb,kt,s): ushort offset nb*131072 + (kt*4+s)*512 + lane*8
  const ushort_t* bbase[3];
#pragma unroll
  for (int nf = 0; nf < 3; ++nf)
    bbase[nf] = gT2 + (size_t)(n0 / 32 + wn * 3 + nf) * 131072 + lane * 8;

  f32x16 acc[4][3];
#pragma unroll
  for (int mr = 0; mr < 4; ++mr)
#pragma unroll
    for (int nf = 0; nf < 3; ++nf)
#pragma unroll
      for (int e = 0; e < 16; ++e) acc[mr][nf][e] = 0.f;

  __syncthreads();                            // publish p1h (only barrier)

  half8 bA[4][3], bB[4][3];
  // prologue: tile 0 -> bA
#pragma unroll
  for (int s = 0; s < 4; ++s)
#pragma unroll
    for (int nf = 0; nf < 3; ++nf)
      bA[s][nf] = *(const half8*)&bbase[nf][(size_t)s * 512];

  for (int io = 0; io < 16; ++io) {           // i-index (p1)
    half2v p1p3h[4][4];
#pragma unroll
    for (int mr = 0; mr < 4; ++mr) {
      union { ushort_t u; _Float16 h; } c;
      c.u = p1h[io * 256 + wm * 128 + mr * 32 + l31];
      const float p1v = (float)c.h;
#pragma unroll
      for (int q = 0; q < 4; ++q)
        p1p3h[mr][q] = cvt_pkrtz2(p1v * p3r[mr][2 * q],
                                  p1v * p3r[mr][2 * q + 1]);
    }
#pragma unroll
    for (int kq = 0; kq < 4; ++kq) {          // kt%2 == kq%2 (static parity)
      const int kt = io * 4 + kq;
      // issue loads for kt+1 into the OTHER buffer (consumed next body)
      if (kt < 63) {
        if ((kq & 1) == 0) {
#pragma unroll
          for (int s = 0; s < 4; ++s)
#pragma unroll
            for (int nf = 0; nf < 3; ++nf)
              bB[s][nf] = *(const half8*)&bbase[nf][(size_t)((kt + 1) * 4 + s) * 512];
        } else {
#pragma unroll
          for (int s = 0; s < 4; ++s)
#pragma unroll
            for (int nf = 0; nf < 3; ++nf)
              bA[s][nf] = *(const half8*)&bbase[nf][(size_t)((kt + 1) * 4 + s) * 512];
        }
      }

#pragma unroll
      for (int s = 0; s < 4; ++s) {
        const int j = kq * 4 + s;             // static p2 index
        half8 a[4];
#pragma unroll
        for (int mr = 0; mr < 4; ++mr) {
          union { half2v h2[4]; half8 h8; } pk;
#pragma unroll
          for (int q = 0; q < 4; ++q) pk.h2[q] = p2h[mr][j] * p1p3h[mr][q];
          a[mr] = pk.h8;
        }
        __builtin_amdgcn_s_setprio(1);
#pragma unroll
        for (int mr = 0; mr < 4; ++mr)
#pragma unroll
          for (int nf = 0; nf < 3; ++nf)
            acc[mr][nf] = __builtin_amdgcn_mfma_f32_32x32x16_f16(
                a[mr], (kq & 1) ? bB[s][nf] : bA[s][nf], acc[mr][nf], 0, 0, 0);
        __builtin_amdgcn_s_setprio(0);
      }
    }
  }

  // epilogue: 32x32 C/D: col = lane&31, row = (reg&3)+8*(reg>>2)+4*(lane>>5)
#pragma unroll
  for (int mr = 0; mr < 4; ++mr)
#pragma unroll
    for (int nf = 0; nf < 3; ++nf)
#pragma unroll
      for (int reg = 0; reg < 16; ++reg) {
        const int row = (reg & 3) + 8 * (reg >> 2) + 4 * g;
        const int t = m0 + wm * 128 + mr * 32 + row;
        out[(size_t)t * 768 + n0 + wn * 96 + nf * 32 + l31] = acc[mr][nf][reg];
      }
}

// ---------------------------------------------------------------------------
extern "C" void kernel_launch(void* const* d_in, const int* in_sizes, int n_in,
                              void* d_out, int out_size, void* d_ws, size_t ws_size,
                              hipStream_t stream) {
  (void)in_sizes; (void)n_in; (void)out_size; (void)ws_size;
  const float* x    = (const float*)d_in[0];
  const float* W1   = (const float*)d_in[1];
  const float* b1   = (const float*)d_in[2];
  const float* W2   = (const float*)d_in[3];
  const float* b2   = (const float*)d_in[4];
  const float* W3   = (const float*)d_in[5];
  const float* b3   = (const float*)d_in[6];
  const float* grid = (const float*)d_in[7];
  const float* temp = (const float*)d_in[8];
  float* out = (float*)d_out;

  // ws: gT2 f16 fragment-ordered = 6,291,456 B ; p f32 [16384][52] = 3,407,872 B
  ushort_t* gT2 = (ushort_t*)d_ws;
  float* p = (float*)((char*)d_ws + 6291456);

  k_pack<<<dim3(64, 24), 256, 0, stream>>>(grid, gT2);
  k_prep<<<dim3(256), 512, 0, stream>>>(x, W1, b1, W2, b2, W3, b3, temp, p);
  k_gemm<<<dim3(64, 4), 256, 0, stream>>>(p, gT2, out);
}

// Round 14
// 106.084 us; speedup vs baseline: 1.4569x; 1.3353x over previous
//
#include <hip/hip_runtime.h>
#include <hip/hip_bf16.h>

// out[t,l] = sum_{ijk} p1[t,i] p2[t,j] p3[t,k] grid[i,j,k,l]
// GEMM M=16384, K=4096 (k=i*256+j*16+kk), N=768; A built in registers.
// v13: k_gemm = round-6 champion (95us) verbatim. k_prep rebuilt as MFMA
//      GEMM (x@W, 16x16x32 f16): W pre-packed into B-fragments, A-frags
//      read DIRECT from global x (coalesced 128B per 4-lane group, x read
//      once), softmax via 16-lane shfl groups. No LDS, no barriers, no
//      scalar-load chain.

using f32x2  = __attribute__((ext_vector_type(2))) float;
using f32x4  = __attribute__((ext_vector_type(4))) float;
using f32x16 = __attribute__((ext_vector_type(16))) float;
using half8  = __attribute__((ext_vector_type(8))) _Float16;
using half2v = __attribute__((ext_vector_type(2))) _Float16;
typedef unsigned short ushort_t;
typedef unsigned int uint_t;

typedef const __attribute__((address_space(1))) void* gptr_t;
typedef __attribute__((address_space(3))) void* lptr_t;

#define PSTRIDE 52            // p row stride (floats)

static __device__ __forceinline__ ushort_t f2h_bits(float x) {
  union { _Float16 h; ushort_t u; } c;
  c.h = (_Float16)x;          // RNE
  return c.u;
}

static __device__ __forceinline__ half2v cvt_pkrtz2(float a, float b) {
  auto r = __builtin_amdgcn_cvt_pkrtz(a, b);
  union { decltype(r) i; half2v o; } u;
  u.i = r;
  return u.o;
}

// ---------------------------------------------------------------------------
// Kernel 1: grid (4096 x 768 f32) -> gT (768 x 4096 f16)  [by = 0..11]
//           + W1/W2/W3 -> wfrag f16 B-fragments             [by = 12, bx<9]
// wfrag layout: frag(ks,nf) at u16 offset (ks*3+nf)*512 + lane*8 + e,
//   value = Wsel[d = ks*32 + 8*(lane>>4) + e][col = lane&15]
// ---------------------------------------------------------------------------
__global__ __launch_bounds__(256) void k_pack(const float* __restrict__ g,
                                              ushort_t* __restrict__ gT,
                                              const float* __restrict__ W1,
                                              const float* __restrict__ W2,
                                              const float* __restrict__ W3,
                                              ushort_t* __restrict__ wfrag) {
  const int tx = threadIdx.x;
  if (blockIdx.y == 12) {
    if (blockIdx.x >= 9) return;
#pragma unroll
    for (int j = 0; j < 16; ++j) {
      const int u = blockIdx.x * 4096 + tx * 16 + j;   // 0..36863
      const int e = u & 7;
      const int l = (u >> 3) & 63;
      const int frag = u >> 9;                         // ks*3+nf
      const int ks = frag / 3, nf = frag % 3;
      const int d = ks * 32 + 8 * (l >> 4) + e;
      const int col = l & 15;
      const float* Wsel = (nf == 0) ? W1 : (nf == 1) ? W2 : W3;
      wfrag[u] = f2h_bits(Wsel[d * 16 + col]);
    }
    return;
  }
  __shared__ ushort_t tile[64][65];
  const int r0 = blockIdx.x * 64;   // ijk base
  const int c0 = blockIdx.y * 64;   // l base
#pragma unroll
  for (int it = 0; it < 4; ++it) {
    const int idx = tx + it * 256;
    const int r = idx >> 4;
    const int c = (idx & 15) << 2;
    const float4 v = *(const float4*)(g + (size_t)(r0 + r) * 768 + (c0 + c));
    tile[c + 0][r] = f2h_bits(v.x);
    tile[c + 1][r] = f2h_bits(v.y);
    tile[c + 2][r] = f2h_bits(v.z);
    tile[c + 3][r] = f2h_bits(v.w);
  }
  __syncthreads();
#pragma unroll
  for (int it = 0; it < 4; ++it) {
    const int idx = tx + it * 256;
    const int r = idx >> 4;
    const int c = (idx & 15) << 2;
    ushort4 o;
    o.x = tile[r][c + 0]; o.y = tile[r][c + 1];
    o.z = tile[r][c + 2]; o.w = tile[r][c + 3];
    *(ushort4*)(gT + (size_t)(c0 + r) * 4096 + (r0 + c)) = o;
  }
}

// ---------------------------------------------------------------------------
// Kernel 2: MFMA prep. p[t][48] = softmax16((x@W + b)/temp) per 16-group.
// 256 blocks x 256 thr; wave owns 16 tokens. A-frags direct from global x
// (f32 -> cvt_pkrtz f16); W B-frags from wfrag (L1-hot, shared by all).
// 72 MFMA 16x16x32 per wave; softmax via shfl_xor over 16-lane groups.
// ---------------------------------------------------------------------------
__global__ __launch_bounds__(256) void k_prep(const float* __restrict__ x,
                                              const ushort_t* __restrict__ wfrag,
                                              const float* __restrict__ b1,
                                              const float* __restrict__ b2,
                                              const float* __restrict__ b3,
                                              const float* __restrict__ temp,
                                              float* __restrict__ p) {
  const int tid = threadIdx.x;
  const int lane = tid & 63;
  const int wv = tid >> 6;
  const int t0w = blockIdx.x * 64 + wv * 16;  // wave's token base
  const int m = lane & 15;                    // A row / C col
  const int q = lane >> 4;                    // 0..3

  // A-frag source: token t0w+m, d0 = ks*32 + q*8
  const float* xrow = x + (size_t)(t0w + m) * 768 + q * 8;

  f32x4 acc[3];
#pragma unroll
  for (int nf = 0; nf < 3; ++nf) acc[nf] = (f32x4){0.f, 0.f, 0.f, 0.f};

  const ushort_t* wf = wfrag + lane * 8;
#pragma unroll
  for (int ks = 0; ks < 24; ++ks) {
    const f32x4 xa = *(const f32x4*)(xrow + ks * 32);
    const f32x4 xb = *(const f32x4*)(xrow + ks * 32 + 4);
    union { half2v h2[4]; half8 h8; } pk;
    pk.h2[0] = cvt_pkrtz2(xa[0], xa[1]);
    pk.h2[1] = cvt_pkrtz2(xa[2], xa[3]);
    pk.h2[2] = cvt_pkrtz2(xb[0], xb[1]);
    pk.h2[3] = cvt_pkrtz2(xb[2], xb[3]);
    const half8 a = pk.h8;
#pragma unroll
    for (int nf = 0; nf < 3; ++nf) {
      const half8 w = *(const half8*)&wf[(size_t)(ks * 3 + nf) * 512];
      acc[nf] = __builtin_amdgcn_mfma_f32_16x16x32_f16(a, w, acc[nf], 0, 0, 0);
    }
  }

  // z[nf][reg] = (acc + bias)*invT ; C: row = 4q+reg (token), col = m
  const float invT = 1.0f / temp[0];
  float z[3][4];
  const float bias[3] = {b1[m], b2[m], b3[m]};
#pragma unroll
  for (int nf = 0; nf < 3; ++nf)
#pragma unroll
    for (int r = 0; r < 4; ++r) z[nf][r] = (acc[nf][r] + bias[nf]) * invT;

  // per-row (token) softmax over 48 cols: 16-lane groups share a row-set
#pragma unroll
  for (int grp = 0; grp < 3; ++grp) {        // p1/p2/p3 independent softmax
    float mx[4], sm[4];
#pragma unroll
    for (int r = 0; r < 4; ++r) mx[r] = z[grp][r];
#pragma unroll
    for (int msk = 1; msk < 16; msk <<= 1)
#pragma unroll
      for (int r = 0; r < 4; ++r) mx[r] = fmaxf(mx[r], __shfl_xor(mx[r], msk));
#pragma unroll
    for (int r = 0; r < 4; ++r) { z[grp][r] = __expf(z[grp][r] - mx[r]); sm[r] = z[grp][r]; }
#pragma unroll
    for (int msk = 1; msk < 16; msk <<= 1)
#pragma unroll
      for (int r = 0; r < 4; ++r) sm[r] += __shfl_xor(sm[r], msk);
#pragma unroll
    for (int r = 0; r < 4; ++r) z[grp][r] /= sm[r];
  }

  // write p: token = t0w + 4q + r, col = grp*16 + m  (16-lane rows coalesce)
#pragma unroll
  for (int r = 0; r < 4; ++r) {
    float* prow = p + (size_t)(t0w + 4 * q + r) * PSTRIDE + m;
#pragma unroll
    for (int grp = 0; grp < 3; ++grp) prow[grp * 16] = z[grp][r];
  }
}

// ---------------------------------------------------------------------------
// Kernel 3: GEMM — round-6 champion verbatim (95 us). BM=128 BN=192 BK=64,
// 4 waves 2x2, wave tile 64x96, mfma_32x32x16_f16, 2-buffer drain schedule,
// setprio MFMA clusters, XCD swizzle.
// ---------------------------------------------------------------------------
__global__ __launch_bounds__(256, 2) void k_gemm(const float* __restrict__ p_g,
                                                 const ushort_t* __restrict__ gT,
                                                 float* __restrict__ out) {
  __shared__ ushort_t Bt[2][192 * 64];        // 49,152 B
  __shared__ float p1T[16 * 128];             //  8,192 B

  const int tid = threadIdx.x;
  const int lane = tid & 63;
  const int wv = __builtin_amdgcn_readfirstlane(tid >> 6);
  const int wm = wv >> 1, wn = wv & 1;
  const int g = lane >> 5;                    // k-half 0/1
  const int l31 = lane & 31;

  // XCD-aware swizzle over 512 blocks (512 % 8 == 0 -> bijective)
  const int f = blockIdx.y * 128 + blockIdx.x;
  const int w = (f & 7) * 64 + (f >> 3);
  const int m0 = (w & 127) * 128;
  const int n0 = (w >> 7) * 192;

  // p1T[i][row] cooperative build (f32)
  if (tid < 128) {
    const float* pr = p_g + (size_t)(m0 + tid) * PSTRIDE;
#pragma unroll
    for (int qq = 0; qq < 4; ++qq) {
      const f32x4 v = *(const f32x4*)(pr + qq * 4);
#pragma unroll
      for (int e = 0; e < 4; ++e) p1T[(qq * 4 + e) * 128 + tid] = v[e];
    }
  }

  // per-lane p2 (16 f16-broadcast pairs) and p3 (own k-half, 8 f32) per m-rep
  const int rowA0 = m0 + wm * 64 + l31;
  half2v p2h[2][16];
  float p3r[2][8];
#pragma unroll
  for (int mr = 0; mr < 2; ++mr) {
    const float* pr = p_g + (size_t)(rowA0 + mr * 32) * PSTRIDE;
#pragma unroll
    for (int qq = 0; qq < 4; ++qq) {
      const f32x4 v = *(const f32x4*)(pr + 16 + qq * 4);
#pragma unroll
      for (int e = 0; e < 4; ++e)
        p2h[mr][qq * 4 + e] = cvt_pkrtz2(v[e], v[e]);
    }
#pragma unroll
    for (int qq = 0; qq < 2; ++qq) {
      const f32x4 v = *(const f32x4*)(pr + 32 + 8 * g + qq * 4);
      p3r[mr][qq * 4 + 0] = v[0]; p3r[mr][qq * 4 + 1] = v[1];
      p3r[mr][qq * 4 + 2] = v[2]; p3r[mr][qq * 4 + 3] = v[3];
    }
  }

  // B staging: linear LDS dest + inverse-swizzled source (16B chunks)
  const int srow = wv * 48 + (lane >> 3);
  const int schunk = (lane & 7) ^ (lane >> 3);
  const ushort_t* sbase = gT + (size_t)(n0 + srow) * 4096 + schunk * 8;
  auto stage = [&](int buf, int kt) {
    const ushort_t* src = sbase + kt * 64;
#pragma unroll
    for (int qq = 0; qq < 6; ++qq) {
      __builtin_amdgcn_global_load_lds((gptr_t)(src + (size_t)qq * 8 * 4096),
                                       (lptr_t)&Bt[buf][(wv * 48 + qq * 8) * 64], 16, 0, 0);
    }
  };

  f32x16 acc[2][3];
#pragma unroll
  for (int mr = 0; mr < 2; ++mr)
#pragma unroll
    for (int nf = 0; nf < 3; ++nf)
#pragma unroll
      for (int e = 0; e < 16; ++e) acc[mr][nf][e] = 0.f;

  stage(0, 0);
  asm volatile("s_waitcnt vmcnt(0) lgkmcnt(0)" ::: "memory");
  __builtin_amdgcn_s_barrier();

  const int rowLoc0 = wm * 64 + l31;
  for (int io = 0; io < 16; ++io) {           // i-index (p1)
    half2v p1p3h[2][4];
#pragma unroll
    for (int mr = 0; mr < 2; ++mr) {
      const float p1v = p1T[io * 128 + rowLoc0 + mr * 32];
#pragma unroll
      for (int qq = 0; qq < 4; ++qq)
        p1p3h[mr][qq] = cvt_pkrtz2(p1v * p3r[mr][2 * qq],
                                   p1v * p3r[mr][2 * qq + 1]);
    }
#pragma unroll
    for (int kq = 0; kq < 4; ++kq) {
      const int kt = io * 4 + kq;
      const ushort_t* bbuf = Bt[kq & 1];

      // issue all 12 B-fragment reads up front (counted lgkm waits)
      half8 b[4][3];
#pragma unroll
      for (int s = 0; s < 4; ++s) {
        const int cd = 2 * s + g;
#pragma unroll
        for (int nf = 0; nf < 3; ++nf) {
          const int r = wn * 96 + nf * 32 + l31;
          b[s][nf] = *(const half8*)&bbuf[r * 64 + ((cd ^ (r & 7)) << 3)];
        }
      }
      // prefetch next K64 tile
      if (kq < 3 || io < 15) stage((kq + 1) & 1, kt + 1);

#pragma unroll
      for (int s = 0; s < 4; ++s) {
        const int j = kq * 4 + s;             // static p2 index
        half8 a[2];
#pragma unroll
        for (int mr = 0; mr < 2; ++mr) {
          union { half2v h2[4]; half8 h8; } pk;
#pragma unroll
          for (int qq = 0; qq < 4; ++qq) pk.h2[qq] = p2h[mr][j] * p1p3h[mr][qq];
          a[mr] = pk.h8;
        }
        __builtin_amdgcn_s_setprio(1);
#pragma unroll
        for (int mr = 0; mr < 2; ++mr)
#pragma unroll
          for (int nf = 0; nf < 3; ++nf)
            acc[mr][nf] = __builtin_amdgcn_mfma_f32_32x32x16_f16(a[mr], b[s][nf], acc[mr][nf], 0, 0, 0);
        __builtin_amdgcn_s_setprio(0);
      }
      asm volatile("s_waitcnt vmcnt(0)" ::: "memory");
      __builtin_amdgcn_s_barrier();
    }
  }

  // epilogue: 32x32 C/D: col = lane&31, row = (reg&3)+8*(reg>>2)+4*(lane>>5)
#pragma unroll
  for (int mr = 0; mr < 2; ++mr)
#pragma unroll
    for (int nf = 0; nf < 3; ++nf)
#pragma unroll
      for (int reg = 0; reg < 16; ++reg) {
        const int row = (reg & 3) + 8 * (reg >> 2) + 4 * g;
        const int t = m0 + wm * 64 + mr * 32 + row;
        out[(size_t)t * 768 + n0 + wn * 96 + nf * 32 + l31] = acc[mr][nf][reg];
      }
}

// ---------------------------------------------------------------------------
extern "C" void kernel_launch(void* const* d_in, const int* in_sizes, int n_in,
                              void* d_out, int out_size, void* d_ws, size_t ws_size,
                              hipStream_t stream) {
  (void)in_sizes; (void)n_in; (void)out_size; (void)ws_size;
  const float* x    = (const float*)d_in[0];
  const float* W1   = (const float*)d_in[1];
  const float* b1   = (const float*)d_in[2];
  const float* W2   = (const float*)d_in[3];
  const float* b2   = (const float*)d_in[4];
  const float* W3   = (const float*)d_in[5];
  const float* b3   = (const float*)d_in[6];
  const float* grid = (const float*)d_in[7];
  const float* temp = (const float*)d_in[8];
  float* out = (float*)d_out;

  // ws: gT f16 [768][4096] = 6,291,456 B ; p f32 [16384][52] = 3,407,872 B ;
  //     wfrag f16 = 73,728 B
  ushort_t* gT = (ushort_t*)d_ws;
  float* p = (float*)((char*)d_ws + 6291456);
  ushort_t* wfrag = (ushort_t*)((char*)d_ws + 6291456 + 3407872);

  k_pack<<<dim3(64, 13), 256, 0, stream>>>(grid, gT, W1, W2, W3, wfrag);
  k_prep<<<dim3(256), 256, 0, stream>>>(x, wfrag, b1, b2, b3, temp, p);
  k_gemm<<<dim3(128, 4), 256, 0, stream>>>(p, gT, out);
}